// Round 5
// baseline (264.355 us; speedup 1.0000x reference)
//
#include <hip/hip_runtime.h>

// ---------------------------------------------------------------------------
// Causal self-attention, B=4 T=2048 D=1024 H=16 HD=64, fp32 in/out.
// cast x->bf16 ; transpose-cast W ; fused QKV GEMM (N=3072) ;
// flash attention (causal, fixed-offset softmax) ; O GEMM.
// MFMA v_mfma_f32_16x16x32_bf16, HW-verified layouts:
//   A/Bt frag: lane reads row (lane&15), k = (lane>>4)*8 .. +7 (16B contig)
//   C/D:       col = lane&15, row = (lane>>4)*4 + reg
// R9:  attn K/V staged once per block in LDS (traffic /4) + XOR swizzle.
// R10: GEMM BK=64, 128B rows, slot^=(row&7) swizzle -> conflicts 6.3M->0.
// R11: GEMM 2-phase dbuf REGRESSED (occupancy halved). Reverted.
// R12: qkv 256x128@512thr REGRESSED (1 block/CU -> no cross-block overlap
//      at barriers; MfmaUtil 27->20.5). Reverted to R10 here.
//      Totals insensitive to qkv profiled deltas (L3-warm in real run);
//      attn deltas show 1:1 -> optimize attn.
// R13: attn async-STAGE split (T14): all Ks/Vs ds_reads finish in the first
//      half of a chunk (K-frags+QK+V-frags). Barrier there, THEN issue next
//      chunk's gload_lds so it flies under softmax+P-pack+PV (~1000 cyc);
//      end barrier's vmcnt(0) retires already-landed loads. Same 2 barriers
//      per chunk, same 34KB LDS, same 4 blocks/CU.
// ---------------------------------------------------------------------------

#define B_  4
#define T_  2048
#define D_  1024
#define H_  16
#define HD_ 64
#define M_  (B_ * T_)   // 8192 rows

typedef __bf16 bf16x8 __attribute__((ext_vector_type(8)));
typedef float  floatx4 __attribute__((ext_vector_type(4)));

__device__ __forceinline__ unsigned short f2b(float f) {
  unsigned int u = __float_as_uint(f);
  unsigned int r = (u + 0x7fffu + ((u >> 16) & 1u)) >> 16;
  return (unsigned short)r;
}

__device__ __forceinline__ float fast_exp2(float x) {
#if __has_builtin(__builtin_amdgcn_exp2f)
  return __builtin_amdgcn_exp2f(x);   // raw v_exp_f32
#else
  return exp2f(x);
#endif
}

__device__ __forceinline__ void async_ld16(const void* g, void* l) {
  __builtin_amdgcn_global_load_lds(
      (const __attribute__((address_space(1))) void*)g,
      (__attribute__((address_space(3))) void*)l, 16, 0, 0);
}

// --------------------------- prep kernels ----------------------------------

__global__ void cast_fp32_to_bf16(const float* __restrict__ in,
                                  unsigned short* __restrict__ out, int n) {
  int i = (blockIdx.x * 256 + threadIdx.x) * 4;
  if (i >= n) return;
  float4 v = *(const float4*)(in + i);
  ushort4 o;
  o.x = f2b(v.x); o.y = f2b(v.y); o.z = f2b(v.z); o.w = f2b(v.w);
  *(ushort4*)(out + i) = o;
}

__global__ void transpose_cast(const float* __restrict__ W0, const float* __restrict__ W1,
                               const float* __restrict__ W2, const float* __restrict__ W3,
                               unsigned short* __restrict__ O0, unsigned short* __restrict__ O1,
                               unsigned short* __restrict__ O2, unsigned short* __restrict__ O3) {
  __shared__ float tile[32][33];
  int z = blockIdx.z;
  const float* W = z == 0 ? W0 : z == 1 ? W1 : z == 2 ? W2 : W3;
  unsigned short* O = z == 0 ? O0 : z == 1 ? O1 : z == 2 ? O2 : O3;
  int n0 = blockIdx.x * 32, k0 = blockIdx.y * 32;
  int tx = threadIdx.x, ty = threadIdx.y;
#pragma unroll
  for (int i = 0; i < 4; ++i)
    tile[ty + i * 8][tx] = W[(size_t)(k0 + ty + i * 8) * D_ + n0 + tx];
  __syncthreads();
#pragma unroll
  for (int i = 0; i < 4; ++i)
    O[(size_t)(n0 + ty + i * 8) * D_ + k0 + tx] = f2b(tile[tx][ty + i * 8]);
}

// --------------------------- fused QKV GEMM --------------------------------
// A [8192][1024] bf16, Wt [3072][1024] bf16 (Wq^T|Wk^T|Wv^T contiguous).
// Q,K out: bf16 [B][H][T][HD]; V out: bf16 [B][H][HD][Tp] key-permuted.
// R10 structure: 128x128 BK=64, 128B rows, slot^=(row&7) swizzle.

__global__ __launch_bounds__(256, 2)
void gemm_qkv(const unsigned short* __restrict__ A,
              const unsigned short* __restrict__ Wt,
              const float* __restrict__ bq, const float* __restrict__ bk,
              const float* __restrict__ bv,
              unsigned short* __restrict__ Qo, unsigned short* __restrict__ Ko,
              unsigned short* __restrict__ Vo) {
  __shared__ __align__(16) unsigned short As[128 * 64];
  __shared__ __align__(16) unsigned short Bs[128 * 64];
  const int K = D_;

  const int tid = threadIdx.x;
  const int wave = tid >> 6, lane = tid & 63;
  const int quad = lane >> 4, l16 = lane & 15;
  const int m0 = blockIdx.y * 128, n0 = blockIdx.x * 128;
  const int wm = (wave >> 1) * 64, wn = (wave & 1) * 64;

  const int rsub = lane >> 3;                 // 0..7 (row within 8-row group)
  const int csw = ((lane & 7) ^ rsub) * 8;    // inverse-swizzled src col (elems)
  const int rw = wave * 32;                   // this wave's staging row base

  const unsigned short* Ag = A + (size_t)(m0 + rw + rsub) * K + csw;
  const unsigned short* Bg = Wt + (size_t)(n0 + rw + rsub) * K + csw;

  floatx4 acc[4][4] = {};

  for (int kt = 0; kt < K; kt += 64) {
#pragma unroll
    for (int j = 0; j < 4; ++j) {
      async_ld16(Ag + (size_t)(j * 8) * K + kt, &As[(rw + j * 8) * 64]);
      async_ld16(Bg + (size_t)(j * 8) * K + kt, &Bs[(rw + j * 8) * 64]);
    }
    __syncthreads();

#pragma unroll
    for (int kk = 0; kk < 2; ++kk) {
      bf16x8 a[4], b[4];
#pragma unroll
      for (int i = 0; i < 4; ++i) {
        const int ra = wm + i * 16 + l16;
        a[i] = *(const bf16x8*)&As[ra * 64 + (((kk * 4 + quad) ^ (ra & 7)) * 8)];
      }
#pragma unroll
      for (int i = 0; i < 4; ++i) {
        const int rb = wn + i * 16 + l16;
        b[i] = *(const bf16x8*)&Bs[rb * 64 + (((kk * 4 + quad) ^ (rb & 7)) * 8)];
      }
#pragma unroll
      for (int mi = 0; mi < 4; ++mi)
#pragma unroll
        for (int ni = 0; ni < 4; ++ni)
          acc[mi][ni] = __builtin_amdgcn_mfma_f32_16x16x32_bf16(
              a[mi], b[ni], acc[mi][ni], 0, 0, 0);
    }
    __syncthreads();
  }

  const int which = n0 >> 10;  // 0=Q 1=K 2=V (block-uniform)
  const float* bias = which == 0 ? bq : which == 1 ? bk : bv;
  unsigned short* Out = which == 0 ? Qo : which == 1 ? Ko : Vo;

#pragma unroll
  for (int mi = 0; mi < 4; ++mi) {
#pragma unroll
    for (int ni = 0; ni < 4; ++ni) {
#pragma unroll
      for (int r = 0; r < 4; ++r) {
        const int m = m0 + wm + mi * 16 + quad * 4 + r;
        const int n = n0 + wn + ni * 16 + l16;
        const float val = acc[mi][ni][r] + bias[n & 1023];
        const int b = m >> 11, t = m & (T_ - 1);
        const int nl = n & 1023;
        const int h = nl >> 6, d = nl & (HD_ - 1);
        size_t idx;
        if (which == 2) {
          const int tp = (t & ~63) | (((t & 15) << 2) | ((t >> 4) & 3));
          idx = ((size_t)(b * H_ + h) * HD_ + d) * T_ + tp;
        } else {
          idx = ((size_t)(b * H_ + h) * T_ + t) * HD_ + d;
        }
        Out[idx] = f2b(val);
      }
    }
  }
}

// --------------------------- output GEMM (fp32) ----------------------------
// R10 structure (single-buffer 128x128 BK=64, swizzled).

__global__ __launch_bounds__(256, 2)
void gemm_out(const unsigned short* __restrict__ A,
              const unsigned short* __restrict__ Bt,
              const float* __restrict__ bias,
              float* __restrict__ Cout, int N, int K) {
  __shared__ __align__(16) unsigned short As[128 * 64];
  __shared__ __align__(16) unsigned short Bs[128 * 64];

  const int tid = threadIdx.x;
  const int wave = tid >> 6, lane = tid & 63;
  const int quad = lane >> 4, l16 = lane & 15;
  const int m0 = blockIdx.y * 128, n0 = blockIdx.x * 128;
  const int wm = (wave >> 1) * 64, wn = (wave & 1) * 64;

  const int rsub = lane >> 3;
  const int csw = ((lane & 7) ^ rsub) * 8;
  const int rw = wave * 32;

  const unsigned short* Ag = A + (size_t)(m0 + rw + rsub) * K + csw;
  const unsigned short* Bg = Bt + (size_t)(n0 + rw + rsub) * K + csw;

  floatx4 acc[4][4] = {};

  for (int kt = 0; kt < K; kt += 64) {
#pragma unroll
    for (int j = 0; j < 4; ++j) {
      async_ld16(Ag + (size_t)(j * 8) * K + kt, &As[(rw + j * 8) * 64]);
      async_ld16(Bg + (size_t)(j * 8) * K + kt, &Bs[(rw + j * 8) * 64]);
    }
    __syncthreads();

#pragma unroll
    for (int kk = 0; kk < 2; ++kk) {
      bf16x8 a[4], b[4];
#pragma unroll
      for (int i = 0; i < 4; ++i) {
        const int ra = wm + i * 16 + l16;
        a[i] = *(const bf16x8*)&As[ra * 64 + (((kk * 4 + quad) ^ (ra & 7)) * 8)];
      }
#pragma unroll
      for (int i = 0; i < 4; ++i) {
        const int rb = wn + i * 16 + l16;
        b[i] = *(const bf16x8*)&Bs[rb * 64 + (((kk * 4 + quad) ^ (rb & 7)) * 8)];
      }
#pragma unroll
      for (int mi = 0; mi < 4; ++mi)
#pragma unroll
        for (int ni = 0; ni < 4; ++ni)
          acc[mi][ni] = __builtin_amdgcn_mfma_f32_16x16x32_bf16(
              a[mi], b[ni], acc[mi][ni], 0, 0, 0);
    }
    __syncthreads();
  }

#pragma unroll
  for (int mi = 0; mi < 4; ++mi)
#pragma unroll
    for (int ni = 0; ni < 4; ++ni)
#pragma unroll
      for (int r = 0; r < 4; ++r) {
        const int m = m0 + wm + mi * 16 + quad * 4 + r;
        const int n = n0 + wn + ni * 16 + l16;
        Cout[(size_t)m * N + n] = acc[mi][ni][r] + bias[n];
      }
}

// --------------------------- flash attention -------------------------------
// 1024 blocks x 4 waves, one bh per block, consecutive 32-row q-tiles.
// Per 64-key chunk the block stages K[64][64], V[64][64] once in LDS
// (gload_lds, XOR swizzle: phys slot16 = logical ^ (row&7), via linear LDS
// dest + inverse-swizzled global source; reads XOR the same way).
// R13 split schedule per chunk:
//   [K-frags, QK MFMA, V-frags]  (all Ks/Vs ds_reads)
//   barrier                      (readers done)
//   issue stage(kc+1)            (flies under softmax+PV)
//   [softmax, P-pack, PV]        (regs + per-wave Pl only)
//   barrier                      (vmcnt(0) retires landed loads; publishes)
// Fixed-offset softmax p = exp2(s*SL - CB); row-sum l via ones-B MFMA.

#define PSTR 72

__device__ __forceinline__ void attn_qk(
    int quad, int l16,
    const unsigned short* __restrict__ Ks,
    const unsigned short* __restrict__ Vs,
    const bf16x8 (&aq)[2][2], floatx4 (&s)[2][4],
    bf16x8 (&vf0)[4], bf16x8 (&vf1)[4]) {
  const int sw = l16 & 7;

  bf16x8 kf0[4], kf1[4];
#pragma unroll
  for (int j = 0; j < 4; ++j) {
    const unsigned short* kr = &Ks[(j * 16 + l16) * HD_];
    kf0[j] = *(const bf16x8*)&kr[(quad ^ sw) * 8];
    kf1[j] = *(const bf16x8*)&kr[((quad + 4) ^ sw) * 8];
  }

#pragma unroll
  for (int qt = 0; qt < 2; ++qt)
#pragma unroll
    for (int j = 0; j < 4; ++j) {
      s[qt][j] = __builtin_amdgcn_mfma_f32_16x16x32_bf16(aq[qt][0], kf0[j], s[qt][j], 0, 0, 0);
      s[qt][j] = __builtin_amdgcn_mfma_f32_16x16x32_bf16(aq[qt][1], kf1[j], s[qt][j], 0, 0, 0);
    }

#pragma unroll
  for (int d4 = 0; d4 < 4; ++d4) {
    const unsigned short* vr = &Vs[(d4 * 16 + l16) * 64];
    vf0[d4] = *(const bf16x8*)&vr[(quad ^ sw) * 8];
    vf1[d4] = *(const bf16x8*)&vr[((quad + 4) ^ sw) * 8];
  }
}

template <bool MASKED>
__device__ __forceinline__ void attn_sm_pv(
    int kbse, int qw, int quad, int l16,
    floatx4 (&s)[2][4], const bf16x8 (&vf0)[4], const bf16x8 (&vf1)[4],
    floatx4 (&o)[2][4], floatx4 (&lacc)[2],
    unsigned short* __restrict__ pl0, unsigned short* __restrict__ pl1,
    bf16x8 vones) {
  const float SL = 0.125f * 1.44269504f;
  const float CB = 8.0f * 1.44269504f;
#pragma unroll
  for (int qt = 0; qt < 2; ++qt) {
    unsigned short* pw = qt ? pl1 : pl0;
#pragma unroll
    for (int r = 0; r < 4; ++r) {
      float v0 = s[qt][0][r], v1 = s[qt][1][r], v2 = s[qt][2][r], v3 = s[qt][3][r];
      if (MASKED) {
        const int qrow = qw + qt * 16 + quad * 4 + r;
        if (kbse + l16 > qrow)      v0 = -1e30f;
        if (kbse + 16 + l16 > qrow) v1 = -1e30f;
        if (kbse + 32 + l16 > qrow) v2 = -1e30f;
        if (kbse + 48 + l16 > qrow) v3 = -1e30f;
      }
      const float p0 = fast_exp2(__builtin_fmaf(v0, SL, -CB));
      const float p1 = fast_exp2(__builtin_fmaf(v1, SL, -CB));
      const float p2 = fast_exp2(__builtin_fmaf(v2, SL, -CB));
      const float p3 = fast_exp2(__builtin_fmaf(v3, SL, -CB));
      // trunc-bf16 pack: one v_perm per pair; key l16+16i -> slot 4*l16+i
      uint2 pk;
      pk.x = __builtin_amdgcn_perm(__float_as_uint(p1), __float_as_uint(p0), 0x07060302u);
      pk.y = __builtin_amdgcn_perm(__float_as_uint(p3), __float_as_uint(p2), 0x07060302u);
      *(uint2*)&pw[(quad * 4 + r) * PSTR + 4 * l16] = pk;
    }
  }

#pragma unroll
  for (int qt = 0; qt < 2; ++qt) {
    const unsigned short* pw = qt ? pl1 : pl0;
    const bf16x8 pf0 = *(const bf16x8*)&pw[l16 * PSTR + quad * 8];
    const bf16x8 pf1 = *(const bf16x8*)&pw[l16 * PSTR + 32 + quad * 8];
    lacc[qt] = __builtin_amdgcn_mfma_f32_16x16x32_bf16(pf0, vones, lacc[qt], 0, 0, 0);
    lacc[qt] = __builtin_amdgcn_mfma_f32_16x16x32_bf16(pf1, vones, lacc[qt], 0, 0, 0);
#pragma unroll
    for (int d4 = 0; d4 < 4; ++d4) {
      o[qt][d4] = __builtin_amdgcn_mfma_f32_16x16x32_bf16(pf0, vf0[d4], o[qt][d4], 0, 0, 0);
      o[qt][d4] = __builtin_amdgcn_mfma_f32_16x16x32_bf16(pf1, vf1[d4], o[qt][d4], 0, 0, 0);
    }
  }
}

__global__ __launch_bounds__(256, 2)
void attn_kernel(const unsigned short* __restrict__ Q,
                 const unsigned short* __restrict__ K,
                 const unsigned short* __restrict__ Vp,
                 unsigned short* __restrict__ O) {
  __shared__ __align__(16) unsigned short Ks[64 * HD_];   // 8 KB, swizzled
  __shared__ __align__(16) unsigned short Vs[HD_ * 64];   // 8 KB, swizzled
  __shared__ unsigned short Pl[4][2][16 * PSTR];          // 18 KB (per-wave)

  // decode: xcd = b&7 (8 bh each); CU slot = b&255; j = b>>8 picks the
  // complementary group k in {v, 15-v, v+4, 11-v} (cost sum const).
  const int bidx = blockIdx.x;
  const int xcd = bidx & 7;
  const int t = bidx >> 3;            // [0,128)
  const int j = t >> 5;               // [0,4)
  const int slot = t & 31;            // [0,32)
  const int bh_local = slot >> 2;     // [0,8)
  const int v = slot & 3;             // [0,4)
  const int k4 = (j == 0) ? v : (j == 1) ? 15 - v : (j == 2) ? v + 4 : 11 - v;
  const int bh = (xcd << 3) | bh_local;

  const int wave = threadIdx.x >> 6, lane = threadIdx.x & 63;
  const int quad = lane >> 4, l16 = lane & 15;
  const int tile = k4 * 4 + wave;     // [0,64)
  const int qw = tile * 32;

  const unsigned short* Qb = Q + (size_t)bh * T_ * HD_;
  const unsigned short* Kb = K + (size_t)bh * T_ * HD_;
  const unsigned short* Vb = Vp + (size_t)bh * HD_ * T_;

  bf16x8 aq[2][2];
#pragma unroll
  for (int qt = 0; qt < 2; ++qt) {
    const unsigned short* qp = Qb + (size_t)(qw + qt * 16 + l16) * HD_;
    aq[qt][0] = *(const bf16x8*)(qp + quad * 8);
    aq[qt][1] = *(const bf16x8*)(qp + 32 + quad * 8);
  }

  union { unsigned short u[8]; bf16x8 v8; } ones;
#pragma unroll
  for (int i = 0; i < 8; ++i) ones.u[i] = 0x3F80;  // bf16 1.0

  floatx4 o[2][4] = {};
  floatx4 lacc[2] = {};

  // ---- cooperative staging geometry ----
  // gload_lds writes dest = uniform base + lane*16 (linear). Lane l covers
  // LDS (row0 + (l>>3), slot16 l&7). Source column is inverse-swizzled:
  // src slot16 = (l&7) ^ (l>>3)   (row&7 == l>>3 since row0 % 8 == 0).
  const int rsub = lane >> 3;           // 0..7
  const int csw = ((lane & 7) ^ rsub) * 8;  // halves offset within 128B row
  const int rA = 8 * wave;              // rows rA..rA+7   (issue 0)
  const int rB = 8 * (wave + 4);        // rows rB..rB+7   (issue 1)

  const int my_nfull = tile >> 1;       // chunks before the diagonal chunk
  const int nit = 2 * k4 + 2;           // max chunks among block's 4 waves

  // prologue: stage chunk 0
  async_ld16(Kb + (size_t)(rA + rsub) * HD_ + csw, &Ks[rA * HD_]);
  async_ld16(Kb + (size_t)(rB + rsub) * HD_ + csw, &Ks[rB * HD_]);
  async_ld16(Vb + (size_t)(rA + rsub) * T_ + csw, &Vs[rA * 64]);
  async_ld16(Vb + (size_t)(rB + rsub) * T_ + csw, &Vs[rB * 64]);
  __syncthreads();                      // vmcnt(0) drain: chunk 0 visible

  for (int kc = 0; kc < nit; ++kc) {
    const int kbse = kc * 64;
    const bool active = kc <= my_nfull;

    floatx4 s[2][4] = {};
    bf16x8 vf0[4], vf1[4];
    if (active)
      attn_qk(quad, l16, Ks, Vs, aq, s, vf0, vf1);

    __syncthreads();                    // all waves done reading Ks/Vs

    if (kc + 1 < nit) {                 // issue next-chunk staging now;
      const int kn = kbse + 64;         // lands during softmax+PV below
      async_ld16(Kb + (size_t)(kn + rA + rsub) * HD_ + csw, &Ks[rA * HD_]);
      async_ld16(Kb + (size_t)(kn + rB + rsub) * HD_ + csw, &Ks[rB * HD_]);
      async_ld16(Vb + (size_t)(rA + rsub) * T_ + kn + csw, &Vs[rA * 64]);
      async_ld16(Vb + (size_t)(rB + rsub) * T_ + kn + csw, &Vs[rB * 64]);
    }

    if (kc < my_nfull)
      attn_sm_pv<false>(kbse, qw, quad, l16, s, vf0, vf1, o, lacc,
                        &Pl[wave][0][0], &Pl[wave][1][0], ones.v8);
    else if (kc == my_nfull)
      attn_sm_pv<true>(kbse, qw, quad, l16, s, vf0, vf1, o, lacc,
                       &Pl[wave][0][0], &Pl[wave][1][0], ones.v8);

    if (kc + 1 < nit)
      __syncthreads();                  // vmcnt(0): staged chunk kc+1 visible
  }

  const int b = bh >> 4, h = bh & 15;
#pragma unroll
  for (int qt = 0; qt < 2; ++qt) {
#pragma unroll
    for (int r = 0; r < 4; ++r) {
      const float inv = 1.0f / lacc[qt][r];  // every lane holds its row sum
      const int tt = qw + qt * 16 + quad * 4 + r;
      unsigned short* orow = O + (size_t)(b * T_ + tt) * D_ + h * HD_;
      orow[l16]      = f2b(o[qt][0][r] * inv);
      orow[16 + l16] = f2b(o[qt][1][r] * inv);
      orow[32 + l16] = f2b(o[qt][2][r] * inv);
      orow[48 + l16] = f2b(o[qt][3][r] * inv);
    }
  }
}

// --------------------------- launcher --------------------------------------

extern "C" void kernel_launch(void* const* d_in, const int* in_sizes, int n_in,
                              void* d_out, int out_size, void* d_ws, size_t ws_size,
                              hipStream_t stream) {
  const float* x  = (const float*)d_in[0];
  const float* Wq = (const float*)d_in[1];
  const float* bq = (const float*)d_in[2];
  const float* Wk = (const float*)d_in[3];
  const float* bk = (const float*)d_in[4];
  const float* Wv = (const float*)d_in[5];
  const float* bv = (const float*)d_in[6];
  const float* Wo = (const float*)d_in[7];
  const float* bo = (const float*)d_in[8];
  float* out = (float*)d_out;

  char* ws = (char*)d_ws;
  const size_t MB = 1u << 20;
  unsigned short* xb  = (unsigned short*)(ws);              // 16 MB x bf16
  unsigned short* Wqt = (unsigned short*)(ws + 16 * MB);    // 2 MB (Wq^T)
  unsigned short* Wkt = (unsigned short*)(ws + 18 * MB);    // 2 MB (Wk^T) contiguous after Wqt
  unsigned short* Wvt = (unsigned short*)(ws + 20 * MB);    // 2 MB (Wv^T) contiguous after Wkt
  unsigned short* Wot = (unsigned short*)(ws + 22 * MB);    // 2 MB (Wo^T)
  unsigned short* Qb  = (unsigned short*)(ws + 24 * MB);    // 16 MB
  unsigned short* Kb  = (unsigned short*)(ws + 40 * MB);    // 16 MB
  unsigned short* Vtb = (unsigned short*)(ws + 56 * MB);    // 16 MB
  unsigned short* Ob  = xb;  // attn output aliases xb

  cast_fp32_to_bf16<<<dim3(M_ * D_ / 1024), dim3(256), 0, stream>>>(x, xb, M_ * D_);
  transpose_cast<<<dim3(32, 32, 4), dim3(32, 8), 0, stream>>>(
      Wq, Wk, Wv, Wo, Wqt, Wkt, Wvt, Wot);

  gemm_qkv<<<dim3(24, M_ / 128), dim3(256), 0, stream>>>(
      xb, Wqt, bq, bk, bv, Qb, Kb, Vtb);

  attn_kernel<<<dim3(1024), dim3(256), 0, stream>>>(Qb, Kb, Vtb, Ob);

  gemm_out<<<dim3(D_ / 128, M_ / 128), dim3(256), 0, stream>>>(
      Ob, Wot, bo, out, D_, D_);
}

// Round 6
// 257.889 us; speedup vs baseline: 1.0251x; 1.0251x over previous
//
#include <hip/hip_runtime.h>

// ---------------------------------------------------------------------------
// Causal self-attention, B=4 T=2048 D=1024 H=16 HD=64, fp32 in/out.
// cast x->bf16 ; transpose-cast W ; fused QKV GEMM (N=3072) ;
// flash attention (causal, fixed-offset softmax) ; O GEMM.
// MFMA v_mfma_f32_16x16x32_bf16, HW-verified layouts:
//   A/Bt frag: lane reads row (lane&15), k = (lane>>4)*8 .. +7 (16B contig)
//   C/D:       col = lane&15, row = (lane>>4)*4 + reg
// R9:  attn K/V staged once per block in LDS (traffic /4) + XOR swizzle.
// R10: GEMM BK=64, 128B rows, slot^=(row&7) swizzle -> conflicts 6.3M->0.
// R11: GEMM 2-phase dbuf REGRESSED (occupancy halved). Reverted.
// R12: qkv 256x128@512thr REGRESSED (1 block/CU, lockstep). Reverted.
// R13: attn async-STAGE split REGRESSED ~5us (TLP already covered staging
//      latency; split just added reg pressure). Reverted to R9 ordering.
// R14: attn is LDS-throughput bound (24 ds_read_b128/chunk/wave; ~37us of
//      LDS issue per CU). QBLK 32->64 per wave (4x16-row frags): K/V LDS
//      reads amortized over 2x q-rows (LDS issue x0.57), barriers/row /2,
//      blocks 1024->512 so K/V global re-reads /2. Pl -> 4 bufs/wave
//      (LDS 52KB, 2 blocks/CU). Complementary pairing: b,b+256 get
//      k-groups (g,7-g) -> per-CU cost const. GEMMs frozen at R10.
// ---------------------------------------------------------------------------

#define B_  4
#define T_  2048
#define D_  1024
#define H_  16
#define HD_ 64
#define M_  (B_ * T_)   // 8192 rows

typedef __bf16 bf16x8 __attribute__((ext_vector_type(8)));
typedef float  floatx4 __attribute__((ext_vector_type(4)));

__device__ __forceinline__ unsigned short f2b(float f) {
  unsigned int u = __float_as_uint(f);
  unsigned int r = (u + 0x7fffu + ((u >> 16) & 1u)) >> 16;
  return (unsigned short)r;
}

__device__ __forceinline__ float fast_exp2(float x) {
#if __has_builtin(__builtin_amdgcn_exp2f)
  return __builtin_amdgcn_exp2f(x);   // raw v_exp_f32
#else
  return exp2f(x);
#endif
}

__device__ __forceinline__ void async_ld16(const void* g, void* l) {
  __builtin_amdgcn_global_load_lds(
      (const __attribute__((address_space(1))) void*)g,
      (__attribute__((address_space(3))) void*)l, 16, 0, 0);
}

// --------------------------- prep kernels ----------------------------------

__global__ void cast_fp32_to_bf16(const float* __restrict__ in,
                                  unsigned short* __restrict__ out, int n) {
  int i = (blockIdx.x * 256 + threadIdx.x) * 4;
  if (i >= n) return;
  float4 v = *(const float4*)(in + i);
  ushort4 o;
  o.x = f2b(v.x); o.y = f2b(v.y); o.z = f2b(v.z); o.w = f2b(v.w);
  *(ushort4*)(out + i) = o;
}

__global__ void transpose_cast(const float* __restrict__ W0, const float* __restrict__ W1,
                               const float* __restrict__ W2, const float* __restrict__ W3,
                               unsigned short* __restrict__ O0, unsigned short* __restrict__ O1,
                               unsigned short* __restrict__ O2, unsigned short* __restrict__ O3) {
  __shared__ float tile[32][33];
  int z = blockIdx.z;
  const float* W = z == 0 ? W0 : z == 1 ? W1 : z == 2 ? W2 : W3;
  unsigned short* O = z == 0 ? O0 : z == 1 ? O1 : z == 2 ? O2 : O3;
  int n0 = blockIdx.x * 32, k0 = blockIdx.y * 32;
  int tx = threadIdx.x, ty = threadIdx.y;
#pragma unroll
  for (int i = 0; i < 4; ++i)
    tile[ty + i * 8][tx] = W[(size_t)(k0 + ty + i * 8) * D_ + n0 + tx];
  __syncthreads();
#pragma unroll
  for (int i = 0; i < 4; ++i)
    O[(size_t)(n0 + ty + i * 8) * D_ + k0 + tx] = f2b(tile[tx][ty + i * 8]);
}

// --------------------------- fused QKV GEMM --------------------------------
// A [8192][1024] bf16, Wt [3072][1024] bf16 (Wq^T|Wk^T|Wv^T contiguous).
// Q,K out: bf16 [B][H][T][HD]; V out: bf16 [B][H][HD][Tp] key-permuted.
// R10 structure: 128x128 BK=64, 128B rows, slot^=(row&7) swizzle.

__global__ __launch_bounds__(256, 2)
void gemm_qkv(const unsigned short* __restrict__ A,
              const unsigned short* __restrict__ Wt,
              const float* __restrict__ bq, const float* __restrict__ bk,
              const float* __restrict__ bv,
              unsigned short* __restrict__ Qo, unsigned short* __restrict__ Ko,
              unsigned short* __restrict__ Vo) {
  __shared__ __align__(16) unsigned short As[128 * 64];
  __shared__ __align__(16) unsigned short Bs[128 * 64];
  const int K = D_;

  const int tid = threadIdx.x;
  const int wave = tid >> 6, lane = tid & 63;
  const int quad = lane >> 4, l16 = lane & 15;
  const int m0 = blockIdx.y * 128, n0 = blockIdx.x * 128;
  const int wm = (wave >> 1) * 64, wn = (wave & 1) * 64;

  const int rsub = lane >> 3;                 // 0..7 (row within 8-row group)
  const int csw = ((lane & 7) ^ rsub) * 8;    // inverse-swizzled src col (elems)
  const int rw = wave * 32;                   // this wave's staging row base

  const unsigned short* Ag = A + (size_t)(m0 + rw + rsub) * K + csw;
  const unsigned short* Bg = Wt + (size_t)(n0 + rw + rsub) * K + csw;

  floatx4 acc[4][4] = {};

  for (int kt = 0; kt < K; kt += 64) {
#pragma unroll
    for (int j = 0; j < 4; ++j) {
      async_ld16(Ag + (size_t)(j * 8) * K + kt, &As[(rw + j * 8) * 64]);
      async_ld16(Bg + (size_t)(j * 8) * K + kt, &Bs[(rw + j * 8) * 64]);
    }
    __syncthreads();

#pragma unroll
    for (int kk = 0; kk < 2; ++kk) {
      bf16x8 a[4], b[4];
#pragma unroll
      for (int i = 0; i < 4; ++i) {
        const int ra = wm + i * 16 + l16;
        a[i] = *(const bf16x8*)&As[ra * 64 + (((kk * 4 + quad) ^ (ra & 7)) * 8)];
      }
#pragma unroll
      for (int i = 0; i < 4; ++i) {
        const int rb = wn + i * 16 + l16;
        b[i] = *(const bf16x8*)&Bs[rb * 64 + (((kk * 4 + quad) ^ (rb & 7)) * 8)];
      }
#pragma unroll
      for (int mi = 0; mi < 4; ++mi)
#pragma unroll
        for (int ni = 0; ni < 4; ++ni)
          acc[mi][ni] = __builtin_amdgcn_mfma_f32_16x16x32_bf16(
              a[mi], b[ni], acc[mi][ni], 0, 0, 0);
    }
    __syncthreads();
  }

  const int which = n0 >> 10;  // 0=Q 1=K 2=V (block-uniform)
  const float* bias = which == 0 ? bq : which == 1 ? bk : bv;
  unsigned short* Out = which == 0 ? Qo : which == 1 ? Ko : Vo;

#pragma unroll
  for (int mi = 0; mi < 4; ++mi) {
#pragma unroll
    for (int ni = 0; ni < 4; ++ni) {
#pragma unroll
      for (int r = 0; r < 4; ++r) {
        const int m = m0 + wm + mi * 16 + quad * 4 + r;
        const int n = n0 + wn + ni * 16 + l16;
        const float val = acc[mi][ni][r] + bias[n & 1023];
        const int b = m >> 11, t = m & (T_ - 1);
        const int nl = n & 1023;
        const int h = nl >> 6, d = nl & (HD_ - 1);
        size_t idx;
        if (which == 2) {
          const int tp = (t & ~63) | (((t & 15) << 2) | ((t >> 4) & 3));
          idx = ((size_t)(b * H_ + h) * HD_ + d) * T_ + tp;
        } else {
          idx = ((size_t)(b * H_ + h) * T_ + t) * HD_ + d;
        }
        Out[idx] = f2b(val);
      }
    }
  }
}

// --------------------------- output GEMM (fp32) ----------------------------
// R10 structure (single-buffer 128x128 BK=64, swizzled).

__global__ __launch_bounds__(256, 2)
void gemm_out(const unsigned short* __restrict__ A,
              const unsigned short* __restrict__ Bt,
              const float* __restrict__ bias,
              float* __restrict__ Cout, int N, int K) {
  __shared__ __align__(16) unsigned short As[128 * 64];
  __shared__ __align__(16) unsigned short Bs[128 * 64];

  const int tid = threadIdx.x;
  const int wave = tid >> 6, lane = tid & 63;
  const int quad = lane >> 4, l16 = lane & 15;
  const int m0 = blockIdx.y * 128, n0 = blockIdx.x * 128;
  const int wm = (wave >> 1) * 64, wn = (wave & 1) * 64;

  const int rsub = lane >> 3;
  const int csw = ((lane & 7) ^ rsub) * 8;
  const int rw = wave * 32;

  const unsigned short* Ag = A + (size_t)(m0 + rw + rsub) * K + csw;
  const unsigned short* Bg = Bt + (size_t)(n0 + rw + rsub) * K + csw;

  floatx4 acc[4][4] = {};

  for (int kt = 0; kt < K; kt += 64) {
#pragma unroll
    for (int j = 0; j < 4; ++j) {
      async_ld16(Ag + (size_t)(j * 8) * K + kt, &As[(rw + j * 8) * 64]);
      async_ld16(Bg + (size_t)(j * 8) * K + kt, &Bs[(rw + j * 8) * 64]);
    }
    __syncthreads();

#pragma unroll
    for (int kk = 0; kk < 2; ++kk) {
      bf16x8 a[4], b[4];
#pragma unroll
      for (int i = 0; i < 4; ++i) {
        const int ra = wm + i * 16 + l16;
        a[i] = *(const bf16x8*)&As[ra * 64 + (((kk * 4 + quad) ^ (ra & 7)) * 8)];
      }
#pragma unroll
      for (int i = 0; i < 4; ++i) {
        const int rb = wn + i * 16 + l16;
        b[i] = *(const bf16x8*)&Bs[rb * 64 + (((kk * 4 + quad) ^ (rb & 7)) * 8)];
      }
#pragma unroll
      for (int mi = 0; mi < 4; ++mi)
#pragma unroll
        for (int ni = 0; ni < 4; ++ni)
          acc[mi][ni] = __builtin_amdgcn_mfma_f32_16x16x32_bf16(
              a[mi], b[ni], acc[mi][ni], 0, 0, 0);
    }
    __syncthreads();
  }

#pragma unroll
  for (int mi = 0; mi < 4; ++mi)
#pragma unroll
    for (int ni = 0; ni < 4; ++ni)
#pragma unroll
      for (int r = 0; r < 4; ++r) {
        const int m = m0 + wm + mi * 16 + quad * 4 + r;
        const int n = n0 + wn + ni * 16 + l16;
        Cout[(size_t)m * N + n] = acc[mi][ni][r] + bias[n];
      }
}

// --------------------------- flash attention -------------------------------
// R14: 512 blocks x 4 waves; each wave owns a 64-row q-tile (4x16-row
// fragments). Per 64-key chunk the block stages K[64][64], V[64][64] once
// in LDS (gload_lds, XOR swizzle: phys slot16 = logical ^ (row&7), linear
// LDS dest + inverse-swizzled global source; matching XOR on reads).
// Per chunk per wave: K-frags(8 b128) -> per-qt {QK(8 MFMA), fixed-offset
// softmax, P-pack} -> V-frags(8 b128) -> per-qt {lacc ones-MFMA, PV}.
// K/V LDS reads amortized over 64 rows (was 32). Decode: xcd = b&7;
// i=b>>3: bh_local=i&7, g=i>>3, kg = g<4 ? g : 11-g; blocks b,b+256 pair
// k-groups (g,7-g) -> per-CU-slot cost const; wave w tile = kg*4+w.

#define PSTR 72

template <bool MASKED>
__device__ __forceinline__ void attn_chunk64(
    int kbse, int qw, int quad, int l16,
    const unsigned short* __restrict__ Ks,
    const unsigned short* __restrict__ Vs,
    const bf16x8 (&aq)[4][2], floatx4 (&o)[4][4], floatx4 (&lacc)[4],
    unsigned short* __restrict__ plw,   // Pl[wave][0], 4 bufs of 16*PSTR
    bf16x8 vones) {
  const int sw = l16 & 7;

  // ---- K fragments from LDS (swizzled) ----
  bf16x8 kf0[4], kf1[4];
#pragma unroll
  for (int j = 0; j < 4; ++j) {
    const unsigned short* kr = &Ks[(j * 16 + l16) * HD_];
    kf0[j] = *(const bf16x8*)&kr[(quad ^ sw) * 8];
    kf1[j] = *(const bf16x8*)&kr[((quad + 4) ^ sw) * 8];
  }

  const float SL = 0.125f * 1.44269504f;
  const float CB = 8.0f * 1.44269504f;

  // ---- per-qt: QK^T, softmax, P pack ----
#pragma unroll
  for (int qt = 0; qt < 4; ++qt) {
    floatx4 s[4] = {};
#pragma unroll
    for (int j = 0; j < 4; ++j) {
      s[j] = __builtin_amdgcn_mfma_f32_16x16x32_bf16(aq[qt][0], kf0[j], s[j], 0, 0, 0);
      s[j] = __builtin_amdgcn_mfma_f32_16x16x32_bf16(aq[qt][1], kf1[j], s[j], 0, 0, 0);
    }
    unsigned short* pw = plw + qt * (16 * PSTR);
#pragma unroll
    for (int r = 0; r < 4; ++r) {
      float v0 = s[0][r], v1 = s[1][r], v2 = s[2][r], v3 = s[3][r];
      if (MASKED) {
        const int qrow = qw + qt * 16 + quad * 4 + r;
        if (kbse + l16 > qrow)      v0 = -1e30f;
        if (kbse + 16 + l16 > qrow) v1 = -1e30f;
        if (kbse + 32 + l16 > qrow) v2 = -1e30f;
        if (kbse + 48 + l16 > qrow) v3 = -1e30f;
      }
      const float p0 = fast_exp2(__builtin_fmaf(v0, SL, -CB));
      const float p1 = fast_exp2(__builtin_fmaf(v1, SL, -CB));
      const float p2 = fast_exp2(__builtin_fmaf(v2, SL, -CB));
      const float p3 = fast_exp2(__builtin_fmaf(v3, SL, -CB));
      // trunc-bf16 pack: one v_perm per pair; key l16+16i -> slot 4*l16+i
      uint2 pk;
      pk.x = __builtin_amdgcn_perm(__float_as_uint(p1), __float_as_uint(p0), 0x07060302u);
      pk.y = __builtin_amdgcn_perm(__float_as_uint(p3), __float_as_uint(p2), 0x07060302u);
      *(uint2*)&pw[(quad * 4 + r) * PSTR + 4 * l16] = pk;
    }
  }

  // ---- V fragments from LDS ----
  bf16x8 vf0[4], vf1[4];
#pragma unroll
  for (int d4 = 0; d4 < 4; ++d4) {
    const unsigned short* vr = &Vs[(d4 * 16 + l16) * 64];
    vf0[d4] = *(const bf16x8*)&vr[(quad ^ sw) * 8];
    vf1[d4] = *(const bf16x8*)&vr[((quad + 4) ^ sw) * 8];
  }

  // ---- per-qt: P (A-frag) x V ; row-sum via ones-B MFMA ----
#pragma unroll
  for (int qt = 0; qt < 4; ++qt) {
    const unsigned short* pw = plw + qt * (16 * PSTR);
    const bf16x8 pf0 = *(const bf16x8*)&pw[l16 * PSTR + quad * 8];
    const bf16x8 pf1 = *(const bf16x8*)&pw[l16 * PSTR + 32 + quad * 8];
    lacc[qt] = __builtin_amdgcn_mfma_f32_16x16x32_bf16(pf0, vones, lacc[qt], 0, 0, 0);
    lacc[qt] = __builtin_amdgcn_mfma_f32_16x16x32_bf16(pf1, vones, lacc[qt], 0, 0, 0);
#pragma unroll
    for (int d4 = 0; d4 < 4; ++d4) {
      o[qt][d4] = __builtin_amdgcn_mfma_f32_16x16x32_bf16(pf0, vf0[d4], o[qt][d4], 0, 0, 0);
      o[qt][d4] = __builtin_amdgcn_mfma_f32_16x16x32_bf16(pf1, vf1[d4], o[qt][d4], 0, 0, 0);
    }
  }
}

__global__ __launch_bounds__(256, 2)
void attn_kernel(const unsigned short* __restrict__ Q,
                 const unsigned short* __restrict__ K,
                 const unsigned short* __restrict__ Vp,
                 unsigned short* __restrict__ O) {
  __shared__ __align__(16) unsigned short Ks[64 * HD_];   // 8 KB, swizzled
  __shared__ __align__(16) unsigned short Vs[HD_ * 64];   // 8 KB, swizzled
  __shared__ unsigned short Pl[4][4][16 * PSTR];          // 36 KB (per-wave x qt)

  // decode: xcd = b&7 (8 bh each); i = b>>3 in [0,64): bh_local = i&7,
  // g = i>>3; kg = g<4 ? g : 11-g  (covers 0..7 per bh). Blocks b and
  // b+256 pair k-groups (g, 7-g): nit sum = 36 const per CU slot.
  const int bidx = blockIdx.x;
  const int xcd = bidx & 7;
  const int i = bidx >> 3;            // [0,64)
  const int bh_local = i & 7;
  const int g = i >> 3;               // [0,8)
  const int kg = (g < 4) ? g : 11 - g;
  const int bh = (xcd << 3) | bh_local;

  const int wave = threadIdx.x >> 6, lane = threadIdx.x & 63;
  const int quad = lane >> 4, l16 = lane & 15;
  const int tile = kg * 4 + wave;     // [0,32)
  const int qw = tile * 64;

  const unsigned short* Qb = Q + (size_t)bh * T_ * HD_;
  const unsigned short* Kb = K + (size_t)bh * T_ * HD_;
  const unsigned short* Vb = Vp + (size_t)bh * HD_ * T_;

  bf16x8 aq[4][2];
#pragma unroll
  for (int qt = 0; qt < 4; ++qt) {
    const unsigned short* qp = Qb + (size_t)(qw + qt * 16 + l16) * HD_;
    aq[qt][0] = *(const bf16x8*)(qp + quad * 8);
    aq[qt][1] = *(const bf16x8*)(qp + 32 + quad * 8);
  }

  union { unsigned short u[8]; bf16x8 v8; } ones;
#pragma unroll
  for (int i2 = 0; i2 < 8; ++i2) ones.u[i2] = 0x3F80;  // bf16 1.0

  floatx4 o[4][4] = {};
  floatx4 lacc[4] = {};

  // ---- cooperative staging geometry ----
  // gload_lds writes dest = uniform base + lane*16 (linear). Lane l covers
  // LDS (row0 + (l>>3), slot16 l&7). Source column is inverse-swizzled:
  // src slot16 = (l&7) ^ (l>>3)   (row&7 == l>>3 since row0 % 8 == 0).
  const int rsub = lane >> 3;           // 0..7
  const int csw = ((lane & 7) ^ rsub) * 8;  // halves offset within 128B row
  const int rA = 8 * wave;              // rows rA..rA+7   (issue 0)
  const int rB = 8 * (wave + 4);        // rows rB..rB+7   (issue 1)

  const int my_nfull = tile;            // chunks before the diagonal chunk
  const int nit = 4 * kg + 4;           // max chunks among block's 4 waves

  for (int kc = 0; kc < nit; ++kc) {
    const int kbse = kc * 64;
    if (kc) __syncthreads();            // prior chunk's readers done
    // stage K chunk [kbse..kbse+64) x [0..64) and V chunk [0..64)d x keys
    async_ld16(Kb + (size_t)(kbse + rA + rsub) * HD_ + csw, &Ks[rA * HD_]);
    async_ld16(Kb + (size_t)(kbse + rB + rsub) * HD_ + csw, &Ks[rB * HD_]);
    async_ld16(Vb + (size_t)(rA + rsub) * T_ + kbse + csw, &Vs[rA * 64]);
    async_ld16(Vb + (size_t)(rB + rsub) * T_ + kbse + csw, &Vs[rB * 64]);
    __syncthreads();                    // implies vmcnt(0) drain

    if (kc < my_nfull)
      attn_chunk64<false>(kbse, qw, quad, l16, Ks, Vs, aq, o, lacc,
                          &Pl[wave][0][0], ones.v8);
    else if (kc == my_nfull)
      attn_chunk64<true>(kbse, qw, quad, l16, Ks, Vs, aq, o, lacc,
                         &Pl[wave][0][0], ones.v8);
    // waves with smaller tiles idle on up to 3 trailing iterations
  }

  const int b = bh >> 4, h = bh & 15;
#pragma unroll
  for (int qt = 0; qt < 4; ++qt) {
#pragma unroll
    for (int r = 0; r < 4; ++r) {
      const float inv = 1.0f / lacc[qt][r];  // every lane holds its row sum
      const int tt = qw + qt * 16 + quad * 4 + r;
      unsigned short* orow = O + (size_t)(b * T_ + tt) * D_ + h * HD_;
      orow[l16]      = f2b(o[qt][0][r] * inv);
      orow[16 + l16] = f2b(o[qt][1][r] * inv);
      orow[32 + l16] = f2b(o[qt][2][r] * inv);
      orow[48 + l16] = f2b(o[qt][3][r] * inv);
    }
  }
}

// --------------------------- launcher --------------------------------------

extern "C" void kernel_launch(void* const* d_in, const int* in_sizes, int n_in,
                              void* d_out, int out_size, void* d_ws, size_t ws_size,
                              hipStream_t stream) {
  const float* x  = (const float*)d_in[0];
  const float* Wq = (const float*)d_in[1];
  const float* bq = (const float*)d_in[2];
  const float* Wk = (const float*)d_in[3];
  const float* bk = (const float*)d_in[4];
  const float* Wv = (const float*)d_in[5];
  const float* bv = (const float*)d_in[6];
  const float* Wo = (const float*)d_in[7];
  const float* bo = (const float*)d_in[8];
  float* out = (float*)d_out;

  char* ws = (char*)d_ws;
  const size_t MB = 1u << 20;
  unsigned short* xb  = (unsigned short*)(ws);              // 16 MB x bf16
  unsigned short* Wqt = (unsigned short*)(ws + 16 * MB);    // 2 MB (Wq^T)
  unsigned short* Wkt = (unsigned short*)(ws + 18 * MB);    // 2 MB (Wk^T) contiguous after Wqt
  unsigned short* Wvt = (unsigned short*)(ws + 20 * MB);    // 2 MB (Wv^T) contiguous after Wkt
  unsigned short* Wot = (unsigned short*)(ws + 22 * MB);    // 2 MB (Wo^T)
  unsigned short* Qb  = (unsigned short*)(ws + 24 * MB);    // 16 MB
  unsigned short* Kb  = (unsigned short*)(ws + 40 * MB);    // 16 MB
  unsigned short* Vtb = (unsigned short*)(ws + 56 * MB);    // 16 MB
  unsigned short* Ob  = xb;  // attn output aliases xb

  cast_fp32_to_bf16<<<dim3(M_ * D_ / 1024), dim3(256), 0, stream>>>(x, xb, M_ * D_);
  transpose_cast<<<dim3(32, 32, 4), dim3(32, 8), 0, stream>>>(
      Wq, Wk, Wv, Wo, Wqt, Wkt, Wvt, Wot);

  gemm_qkv<<<dim3(24, M_ / 128), dim3(256), 0, stream>>>(
      xb, Wqt, bq, bk, bv, Qb, Kb, Vtb);

  attn_kernel<<<dim3(512), dim3(256), 0, stream>>>(Qb, Kb, Vtb, Ob);

  gemm_out<<<dim3(D_ / 128, M_ / 128), dim3(256), 0, stream>>>(
      Ob, Wot, bo, out, D_, D_);
}